// Round 4
// baseline (1275.161 us; speedup 1.0000x reference)
//
#include <hip/hip_runtime.h>
#include <stdint.h>

#define NN 8192
#define FF 256
#define HH 64

// ---------------------------------------------------------------------------
// K1: h = x @ Wt^T + bt (fp32 in, fp32 out), h[node][c]
// block = 256 threads, 32 rows of x per block; grid = 256
// ---------------------------------------------------------------------------
__global__ __launch_bounds__(256) void k1_h(
    const float* __restrict__ x, const float* __restrict__ Wt,
    const float* __restrict__ bt, float* __restrict__ h) {
  __shared__ float sx[32 * 258];   // 32 rows x 256 (+2 pad)
  __shared__ float sw[64 * 258];   // 64 rows x 256 (+2 pad)
  const int t = threadIdx.x;
  const int row0 = blockIdx.x * 32;

  // stage x tile (32 x 256 fp32)
  for (int i = 0; i < 8; ++i) {
    int lin = i * 1024 + t * 4;
    int r = lin >> 8, f = lin & 255;
    float4 v = *(const float4*)(x + (size_t)(row0 + r) * FF + f);
    float* d = &sx[r * 258 + f];
    d[0] = v.x; d[1] = v.y; d[2] = v.z; d[3] = v.w;
  }
  // stage Wt (64 x 256 fp32)
  for (int i = 0; i < 16; ++i) {
    int lin = i * 1024 + t * 4;
    int r = lin >> 8, f = lin & 255;
    float4 v = *(const float4*)(Wt + (size_t)r * FF + f);
    float* d = &sw[r * 258 + f];
    d[0] = v.x; d[1] = v.y; d[2] = v.z; d[3] = v.w;
  }
  __syncthreads();

  const int r  = t & 31;           // row within tile
  const int c0 = (t >> 5) * 8;     // 8 output cols per thread
  float acc[8];
#pragma unroll
  for (int u = 0; u < 8; ++u) acc[u] = bt[c0 + u];

  for (int f = 0; f < FF; f += 2) {
    float2 xv = *(const float2*)&sx[r * 258 + f];
#pragma unroll
    for (int u = 0; u < 8; ++u) {
      float2 wv = *(const float2*)&sw[(c0 + u) * 258 + f];
      acc[u] += xv.x * wv.x + xv.y * wv.y;
    }
  }
#pragma unroll
  for (int u = 0; u < 8; ++u)
    h[(size_t)(row0 + r) * HH + c0 + u] = acc[u];
}

// ---------------------------------------------------------------------------
// K2 (diagnostic, pure VALU fp32): neighbor = (adj @ h) / deg, then fused
// tf = neighbor @ Wp^T + bp, y = x + tf, LayerNorm -> fp32 out.
// block = 256 (4 waves); wave w handles rows w*4..w*4+3; lane = channel.
// grid = 512 (16 rows/block). No MFMA, no bf16 anywhere.
// ---------------------------------------------------------------------------
__global__ __launch_bounds__(256) void k2_attn(
    const float* __restrict__ x, const int* __restrict__ adj,
    const float* __restrict__ h, const float* __restrict__ Wp,
    const float* __restrict__ bp, const float* __restrict__ gamma,
    const float* __restrict__ beta, float* __restrict__ out) {
  __shared__ float s_nb[16][64];    // neighbor (post /deg)
  __shared__ float s_y[16 * 256];   // y = x + tf

  const int t    = threadIdx.x;
  const int w    = t >> 6;       // wave id 0..3
  const int lane = t & 63;       // channel
  const int row0 = blockIdx.x * 16;

  const int* ar0 = adj + (size_t)(row0 + w * 4 + 0) * NN;
  const int* ar1 = adj + (size_t)(row0 + w * 4 + 1) * NN;
  const int* ar2 = adj + (size_t)(row0 + w * 4 + 2) * NN;
  const int* ar3 = adj + (size_t)(row0 + w * 4 + 3) * NN;

  float acc0 = 0.f, acc1 = 0.f, acc2 = 0.f, acc3 = 0.f;
  int d0 = 0, d1 = 0, d2 = 0, d3 = 0;

  for (int jb = 0; jb < NN; jb += 4) {
    int4 a0 = *(const int4*)(ar0 + jb);   // wave-uniform -> scalar loads
    int4 a1 = *(const int4*)(ar1 + jb);
    int4 a2 = *(const int4*)(ar2 + jb);
    int4 a3 = *(const int4*)(ar3 + jb);
    float v0 = h[(size_t)(jb + 0) * HH + lane];
    float v1 = h[(size_t)(jb + 1) * HH + lane];
    float v2 = h[(size_t)(jb + 2) * HH + lane];
    float v3 = h[(size_t)(jb + 3) * HH + lane];

    acc0 += (a0.x ? v0 : 0.f) + (a0.y ? v1 : 0.f) + (a0.z ? v2 : 0.f) + (a0.w ? v3 : 0.f);
    acc1 += (a1.x ? v0 : 0.f) + (a1.y ? v1 : 0.f) + (a1.z ? v2 : 0.f) + (a1.w ? v3 : 0.f);
    acc2 += (a2.x ? v0 : 0.f) + (a2.y ? v1 : 0.f) + (a2.z ? v2 : 0.f) + (a2.w ? v3 : 0.f);
    acc3 += (a3.x ? v0 : 0.f) + (a3.y ? v1 : 0.f) + (a3.z ? v2 : 0.f) + (a3.w ? v3 : 0.f);

    d0 += a0.x + a0.y + a0.z + a0.w;
    d1 += a1.x + a1.y + a1.z + a1.w;
    d2 += a2.x + a2.y + a2.z + a2.w;
    d3 += a3.x + a3.y + a3.z + a3.w;
  }

  s_nb[w * 4 + 0][lane] = (d0 > 0) ? acc0 / (float)d0 : 0.f;
  s_nb[w * 4 + 1][lane] = (d1 > 0) ? acc1 / (float)d1 : 0.f;
  s_nb[w * 4 + 2][lane] = (d2 > 0) ? acc2 / (float)d2 : 0.f;
  s_nb[w * 4 + 3][lane] = (d3 > 0) ? acc3 / (float)d3 : 0.f;
  __syncthreads();

  // tf = neighbor @ Wp^T + bp ; y = x + tf
  {
    const int f = t;   // one output feature per thread
    float wp[64];
    const float* wrow = Wp + (size_t)f * HH;
#pragma unroll
    for (int j = 0; j < 16; ++j) {
      float4 v = *(const float4*)(wrow + j * 4);
      wp[j * 4 + 0] = v.x; wp[j * 4 + 1] = v.y;
      wp[j * 4 + 2] = v.z; wp[j * 4 + 3] = v.w;
    }
    const float bpf = bp[f];
    for (int r = 0; r < 16; ++r) {
      float a = bpf;
#pragma unroll
      for (int k = 0; k < 64; k += 4) {
        float4 nv = *(const float4*)&s_nb[r][k];
        a += nv.x * wp[k] + nv.y * wp[k + 1] + nv.z * wp[k + 2] + nv.w * wp[k + 3];
      }
      float y = x[(size_t)(row0 + r) * FF + f] + a;
      s_y[r * 256 + f] = y;
    }
  }
  __syncthreads();

  // LayerNorm per row; wave w handles rows w*4 .. w*4+3; fp32 output
  for (int i = 0; i < 4; ++i) {
    const int r = w * 4 + i;
    float4 v = *(const float4*)&s_y[r * 256 + lane * 4];
    float sum = v.x + v.y + v.z + v.w;
    float ss  = v.x * v.x + v.y * v.y + v.z * v.z + v.w * v.w;
#pragma unroll
    for (int o = 32; o >= 1; o >>= 1) {
      sum += __shfl_xor(sum, o, 64);
      ss  += __shfl_xor(ss, o, 64);
    }
    const float mu  = sum * (1.0f / 256.0f);
    const float var = ss * (1.0f / 256.0f) - mu * mu;
    const float rs  = rsqrtf(var + 1e-5f);
    const int f0 = lane * 4;
    float4 g = *(const float4*)(gamma + f0);
    float4 b = *(const float4*)(beta + f0);
    float4 o4;
    o4.x = g.x * (v.x - mu) * rs + b.x;
    o4.y = g.y * (v.y - mu) * rs + b.y;
    o4.z = g.z * (v.z - mu) * rs + b.z;
    o4.w = g.w * (v.w - mu) * rs + b.w;
    *(float4*)(out + (size_t)(row0 + r) * FF + f0) = o4;
  }
}

extern "C" void kernel_launch(void* const* d_in, const int* in_sizes, int n_in,
                              void* d_out, int out_size, void* d_ws, size_t ws_size,
                              hipStream_t stream) {
  const float* x     = (const float*)d_in[0];
  const int*   adj   = (const int*)d_in[1];
  const float* Wt    = (const float*)d_in[2];
  const float* bt    = (const float*)d_in[3];
  // d_in[4] = Wa, d_in[5] = ba: provably dead (softmax scores are row-constant)
  const float* Wp    = (const float*)d_in[6];
  const float* bp    = (const float*)d_in[7];
  const float* gamma = (const float*)d_in[8];
  const float* beta  = (const float*)d_in[9];
  float* out = (float*)d_out;
  float* h   = (float*)d_ws;   // 8192*64 fp32 = 2 MB scratch

  k1_h<<<256, 256, 0, stream>>>(x, Wt, bt, h);
  k2_attn<<<512, 256, 0, stream>>>(x, adj, h, Wp, bp, gamma, beta, out);
}

// Round 5
// 986.304 us; speedup vs baseline: 1.2929x; 1.2929x over previous
//
#include <hip/hip_runtime.h>
#include <stdint.h>

#define NN 8192
#define FF 256
#define HH 64

// ---------------------------------------------------------------------------
// K1: h = x @ Wt^T + bt (fp32), h[node][c].
// WtT staged in LDS (stride 65 -> conflict-free), x read via scalar dwordx4.
// block = 256 threads (4 waves); wave handles 8 rows; grid = 256.
// ---------------------------------------------------------------------------
__global__ __launch_bounds__(256) void k1_h(
    const float* __restrict__ x, const float* __restrict__ Wt,
    const float* __restrict__ bt, float* __restrict__ h) {
  __shared__ float wtT[256 * 65];   // wtT[f*65 + c] = Wt[c][f]
  __shared__ float sbt[64];
  const int t = threadIdx.x;
  const int lane = t & 63;
  const int w = t >> 6;

  // stage Wt transposed: element (c=i, f=t); global reads coalesced,
  // LDS write bank = (t*65+i)%32 = (lane+i)%32 -> 2 lanes/bank (free)
  for (int i = 0; i < 64; ++i)
    wtT[t * 65 + i] = Wt[(size_t)i * FF + t];
  if (t < 64) sbt[t] = bt[t];
  __syncthreads();

  const int r0 = blockIdx.x * 32 + w * 8;
  const float binit = sbt[lane];
  float acc[8];
#pragma unroll
  for (int r = 0; r < 8; ++r) acc[r] = binit;

  for (int f4 = 0; f4 < FF; f4 += 4) {
    float4 xs[8];
#pragma unroll
    for (int r = 0; r < 8; ++r)
      xs[r] = *(const float4*)(x + (size_t)(r0 + r) * FF + f4);  // wave-uniform -> s_load
    const float wt0 = wtT[(f4 + 0) * 65 + lane];
    const float wt1 = wtT[(f4 + 1) * 65 + lane];
    const float wt2 = wtT[(f4 + 2) * 65 + lane];
    const float wt3 = wtT[(f4 + 3) * 65 + lane];
#pragma unroll
    for (int r = 0; r < 8; ++r)
      acc[r] += xs[r].x * wt0 + xs[r].y * wt1 + xs[r].z * wt2 + xs[r].w * wt3;
  }
#pragma unroll
  for (int r = 0; r < 8; ++r)
    h[(size_t)(r0 + r) * HH + lane] = acc[r];
}

// ---------------------------------------------------------------------------
// K2: neighbor = (adj @ h)/deg, tf = neighbor @ Wp^T + bp, y = x+tf, LayerNorm.
// block = 256 (4 waves); 8 rows/block; wave w covers k-quarter [w*2048,+2048)
// for ALL 8 rows (8 accs/lane, lane = channel). Cross-wave LDS reduce, then
// the verified epilogue. grid = 1024 (4 blocks/CU, 4 waves/SIMD).
// ---------------------------------------------------------------------------
__global__ __launch_bounds__(256) void k2_attn(
    const float* __restrict__ x, const int* __restrict__ adj,
    const float* __restrict__ h, const float* __restrict__ Wp,
    const float* __restrict__ bp, const float* __restrict__ gamma,
    const float* __restrict__ beta, float* __restrict__ out) {
  __shared__ float s_part[4][8][64];   // per-wave partial neighbor sums (8 KB)
  __shared__ float s_nb[8][64];        // neighbor post /deg (2 KB)
  __shared__ float s_y[8 * 256];       // y = x + tf (8 KB)
  __shared__ int   s_degp[4][8];

  const int t    = threadIdx.x;
  const int w    = t >> 6;       // wave id 0..3
  const int lane = t & 63;       // channel
  const int row0 = blockIdx.x * 8;

  const int kbeg = w * (NN / 4);
  const int kend = kbeg + (NN / 4);

  float acc[8];
  int   deg[8];
#pragma unroll
  for (int r = 0; r < 8; ++r) { acc[r] = 0.f; deg[r] = 0; }

  const int* ap[8];
#pragma unroll
  for (int r = 0; r < 8; ++r) ap[r] = adj + (size_t)(row0 + r) * NN;

  for (int jb = kbeg; jb < kend; jb += 4) {
    const float* hb = h + (size_t)jb * HH + lane;
    float v0 = hb[0 * HH];
    float v1 = hb[1 * HH];
    float v2 = hb[2 * HH];
    float v3 = hb[3 * HH];
#pragma unroll
    for (int r = 0; r < 8; ++r) {
      int4 a = *(const int4*)(ap[r] + jb);    // wave-uniform -> scalar load
      acc[r] += (a.x ? v0 : 0.f) + (a.y ? v1 : 0.f) +
                (a.z ? v2 : 0.f) + (a.w ? v3 : 0.f);
      deg[r] += a.x + a.y + a.z + a.w;
    }
  }

#pragma unroll
  for (int r = 0; r < 8; ++r) s_part[w][r][lane] = acc[r];
  if (lane == 0) {
#pragma unroll
    for (int r = 0; r < 8; ++r) s_degp[w][r] = deg[r];
  }
  __syncthreads();

  // cross-wave reduce + /deg  (512 items, 256 threads)
  for (int idx = t; idx < 8 * 64; idx += 256) {
    int r = idx >> 6, c = idx & 63;
    float s = s_part[0][r][c] + s_part[1][r][c] + s_part[2][r][c] + s_part[3][r][c];
    int d = s_degp[0][r] + s_degp[1][r] + s_degp[2][r] + s_degp[3][r];
    s_nb[r][c] = (d > 0) ? s / (float)d : 0.f;
  }
  __syncthreads();

  // tf = neighbor @ Wp^T + bp ; y = x + tf   (verified pattern)
  {
    const int f = t;   // one output feature per thread
    float wp[64];
    const float* wrow = Wp + (size_t)f * HH;
#pragma unroll
    for (int j = 0; j < 16; ++j) {
      float4 v = *(const float4*)(wrow + j * 4);
      wp[j * 4 + 0] = v.x; wp[j * 4 + 1] = v.y;
      wp[j * 4 + 2] = v.z; wp[j * 4 + 3] = v.w;
    }
    const float bpf = bp[f];
    for (int r = 0; r < 8; ++r) {
      float a = bpf;
#pragma unroll
      for (int k = 0; k < 64; k += 4) {
        float4 nv = *(const float4*)&s_nb[r][k];
        a += nv.x * wp[k] + nv.y * wp[k + 1] + nv.z * wp[k + 2] + nv.w * wp[k + 3];
      }
      float y = x[(size_t)(row0 + r) * FF + f] + a;
      s_y[r * 256 + f] = y;
    }
  }
  __syncthreads();

  // LayerNorm; wave w handles rows w*2, w*2+1  (verified pattern)
  for (int i = 0; i < 2; ++i) {
    const int r = w * 2 + i;
    float4 v = *(const float4*)&s_y[r * 256 + lane * 4];
    float sum = v.x + v.y + v.z + v.w;
    float ss  = v.x * v.x + v.y * v.y + v.z * v.z + v.w * v.w;
#pragma unroll
    for (int o = 32; o >= 1; o >>= 1) {
      sum += __shfl_xor(sum, o, 64);
      ss  += __shfl_xor(ss, o, 64);
    }
    const float mu  = sum * (1.0f / 256.0f);
    const float var = ss * (1.0f / 256.0f) - mu * mu;
    const float rs  = rsqrtf(var + 1e-5f);
    const int f0 = lane * 4;
    float4 g = *(const float4*)(gamma + f0);
    float4 b = *(const float4*)(beta + f0);
    float4 o4;
    o4.x = g.x * (v.x - mu) * rs + b.x;
    o4.y = g.y * (v.y - mu) * rs + b.y;
    o4.z = g.z * (v.z - mu) * rs + b.z;
    o4.w = g.w * (v.w - mu) * rs + b.w;
    *(float4*)(out + (size_t)(row0 + r) * FF + f0) = o4;
  }
}

extern "C" void kernel_launch(void* const* d_in, const int* in_sizes, int n_in,
                              void* d_out, int out_size, void* d_ws, size_t ws_size,
                              hipStream_t stream) {
  const float* x     = (const float*)d_in[0];
  const int*   adj   = (const int*)d_in[1];
  const float* Wt    = (const float*)d_in[2];
  const float* bt    = (const float*)d_in[3];
  // d_in[4] = Wa, d_in[5] = ba: provably dead (softmax scores are row-constant)
  const float* Wp    = (const float*)d_in[6];
  const float* bp    = (const float*)d_in[7];
  const float* gamma = (const float*)d_in[8];
  const float* beta  = (const float*)d_in[9];
  float* out = (float*)d_out;
  float* h   = (float*)d_ws;   // 8192*64 fp32 = 2 MB scratch

  k1_h<<<256, 256, 0, stream>>>(x, Wt, bt, h);
  k2_attn<<<1024, 256, 0, stream>>>(x, adj, h, Wp, bp, gamma, beta, out);
}